// Round 5
// baseline (217.157 us; speedup 1.0000x reference)
//
#include <hip/hip_runtime.h>

// Label attention: out = softmax(H @ W^T) @ W, fused, bf16 MFMA, no-max softmax.
// R3 (2nd resubmit after infra timeouts): LDS-BW-driven redesign. 32x32x16 MFMA
// (half the LDS bytes/FLOP), H in registers (64 VGPR, loaded once), W2 streamed
// global->reg from frag-major images (no LDS), Wt DMA'd from frag-major images
// (linear conflict-free ds_read_b128), P via slot-XOR'd frag-major LDS (2-way
// max). One block does both streams (24 iters) -> 256 blocks, perfect balance.
// Raw s_barrier + counted vmcnt keeps DMA/ring loads in flight.

#define TM 128
#define DD 256
#define THREADS 512
#define TOK 32768

typedef __bf16 bf16t;
typedef bf16t v8bf __attribute__((ext_vector_type(8)));
typedef float v16f __attribute__((ext_vector_type(16)));

// LDS layout
#define WT0   0        // Wt tile buf0: 32 frags * 1KB
#define WT1   32768    // Wt tile buf1
#define P_OFF 65536    // P: 4 wr-groups * 4 kb-frags * 1KB
#define L_OFF 81920    // row sums: 128 * 4B
#define LDS_BYTES 82432

// ws layout: frag-major bf16 images (1KB per wave-frag = 64 lanes * 16B)
#define IWT 0          // intent Wt: 8 tiles * 32KB
#define SWT 262144     // slot  Wt: 16 tiles * 32KB
#define IW2 786432     // intent W2: 8 tiles * 32KB
#define SW2 1048576    // slot  W2: 16 tiles * 32KB

__device__ __forceinline__ unsigned short f2bf(float x) {
    unsigned u = __builtin_bit_cast(unsigned, x);
    unsigned r = u + 0x7fffu + ((u >> 16) & 1u);
    return (unsigned short)(r >> 16);
}

// ---- prep: build frag-major bf16 W images in ws ----
// One wave per 1KB frag. Wt frag (tile it, wc, kk): lane l holds
//   W[it*64 + wc*32 + (l&31)][kk*16 + (l>>5)*8 + j], j=0..7  (16B per lane)
// W2 frag (tile it, kb, db): lane l holds
//   W[it*64 + kb*16 + (l>>5)*8 + j][db*32 + (l&31)]
__global__ __launch_bounds__(256) void prep_w_kernel(
    const float* __restrict__ w_int, const float* __restrict__ w_slot,
    char* __restrict__ wsb)
{
    int t = blockIdx.x * 256 + threadIdx.x;
    int w = t >> 6, lane = t & 63;
    int hi = lane >> 5, l5 = lane & 31;
    union { unsigned short u[8]; uint4 q; } pk;

    if (w < 768) {                       // Wt images (256 intent + 512 slot waves)
        int st   = (w >= 256);
        int widx = w - (st ? 256 : 0);
        int it = widx >> 5, fid = widx & 31;
        int wc = fid >> 4, kk = fid & 15;
        const float* W = st ? w_slot : w_int;
        int n  = it * 64 + wc * 32 + l5;
        int k0 = kk * 16 + hi * 8;
        #pragma unroll
        for (int j = 0; j < 8; ++j) pk.u[j] = f2bf(W[(size_t)n * DD + k0 + j]);
        char* dst = wsb + (st ? SWT : IWT) + (size_t)it * 32768 + fid * 1024 + lane * 16;
        *(uint4*)dst = pk.q;
    } else {                             // W2 images
        int w2 = w - 768;
        int st   = (w2 >= 256);
        int widx = w2 - (st ? 256 : 0);
        int it = widx >> 5, fid = widx & 31;
        int kb = fid >> 3, db = fid & 7;
        const float* W = st ? w_slot : w_int;
        int n0 = it * 64 + kb * 16 + hi * 8;
        int d  = db * 32 + l5;
        #pragma unroll
        for (int j = 0; j < 8; ++j) pk.u[j] = f2bf(W[(size_t)(n0 + j) * DD + d]);
        char* dst = wsb + (st ? SW2 : IW2) + (size_t)it * 32768 + fid * 1024 + lane * 16;
        *(uint4*)dst = pk.q;
    }
}

__global__ __launch_bounds__(THREADS, 2) void label_attn_kernel(
    const float* __restrict__ in_intent,
    const float* __restrict__ in_slot,
    const char* __restrict__ wsb,
    float* __restrict__ out)
{
    extern __shared__ char lds[];

    const int tid  = threadIdx.x;
    const int lane = tid & 63;
    const int wid  = tid >> 6;
    const int wr   = wid >> 1;          // token group (32 rows each)
    const int wc   = wid & 1;           // n-half (GEMM1) / d-half (GEMM2)
    const int hi   = lane >> 5;
    const int l5   = lane & 31;
    const int t0   = blockIdx.x * TM;

    float* lsf = (float*)(lds + L_OFF);

    const float* inps[2] = {in_intent, in_slot};
    const char*  wtb[2]  = {wsb + IWT, wsb + SWT};
    const char*  w2b[2]  = {wsb + IW2, wsb + SW2};
    const int    nits[2] = {8, 16};

    // P write-address invariants (frag-major with bijective slot XOR)
    const int kbl_w = (l5 >> 4) & 1;
    const int hb_w  = (l5 >> 3) & 1;
    const int pw_base = P_OFF + wr * 4096 + (wc * 2 + kbl_w) * 1024 + (l5 & 7) * 2;
    const int pw_sxor = (kbl_w << 2) ^ (hb_w << 1);

    for (int st = 0; st < 2; ++st) {
        __builtin_amdgcn_s_barrier();          // prev stream fully done
        if (tid < TM) lsf[tid] = 0.0f;

        const float* __restrict__ inp = inps[st];
        const char*  __restrict__ wtg = wtb[st];
        const char*  __restrict__ w2g = w2b[st];
        const int niter = nits[st];
        float* __restrict__ outp = out + (size_t)st * TOK * DD;

        // ---- H -> registers (16 A-frags: row = lane&31, k = hi*8 + kk*16) ----
        v8bf h[16];
        {
            const float* hp = inp + (size_t)(t0 + wr * 32 + l5) * DD + hi * 8;
            #pragma unroll
            for (int kk = 0; kk < 16; ++kk) {
                float4 a = *(const float4*)(hp + kk * 16);
                float4 b = *(const float4*)(hp + kk * 16 + 4);
                union { unsigned short u[8]; v8bf v; } pk;
                pk.u[0] = f2bf(a.x); pk.u[1] = f2bf(a.y);
                pk.u[2] = f2bf(a.z); pk.u[3] = f2bf(a.w);
                pk.u[4] = f2bf(b.x); pk.u[5] = f2bf(b.y);
                pk.u[6] = f2bf(b.z); pk.u[7] = f2bf(b.w);
                h[kk] = pk.v;
            }
        }

        // ---- issue DMA: Wt tile 0 -> buf0 (linear, conflict-free) ----
        #pragma unroll
        for (int c = 0; c < 4; ++c) {
            int chunk = wid * 4 + c;
            __builtin_amdgcn_global_load_lds(
                (const __attribute__((address_space(1))) unsigned*)(wtg + chunk * 1024 + lane * 16),
                (__attribute__((address_space(3))) unsigned*)(lds + WT0 + chunk * 1024),
                16, 0, 0);
        }
        __builtin_amdgcn_sched_barrier(0);     // pin: ring loads stay after DMA

        // ---- W2 ring preload (tile 0): 16 frags in registers ----
        v8bf ring[16];
        #pragma unroll
        for (int kb = 0; kb < 4; ++kb)
            #pragma unroll
            for (int db = 0; db < 4; ++db)
                ring[kb * 4 + db] =
                    *(const v8bf*)(w2g + (kb * 8 + wc * 4 + db) * 1024 + lane * 16);

        v16f  o[4] = {};
        float ls[16] = {};

        asm volatile("s_waitcnt vmcnt(16)" ::: "memory");  // DMA done; ring in flight
        __builtin_amdgcn_sched_barrier(0);
        __builtin_amdgcn_s_barrier();

        for (int it = 0; it < niter; ++it) {
            char* wbuf = lds + ((it & 1) ? WT1 : WT0);

            // issue next Wt tile DMA into the other buffer
            if (it + 1 < niter) {
                char* nbuf = lds + ((it & 1) ? WT0 : WT1);
                const char* src = wtg + (size_t)(it + 1) * 32768;
                #pragma unroll
                for (int c = 0; c < 4; ++c) {
                    int chunk = wid * 4 + c;
                    __builtin_amdgcn_global_load_lds(
                        (const __attribute__((address_space(1))) unsigned*)(src + chunk * 1024 + lane * 16),
                        (__attribute__((address_space(3))) unsigned*)(nbuf + chunk * 1024),
                        16, 0, 0);
                }
            }

            // ---- GEMM1: S[32 t][32 n] = H @ Wt^T  (A from regs, B linear LDS) ----
            v16f cacc = {};
            #pragma unroll
            for (int kk = 0; kk < 16; ++kk) {
                v8bf b1 = *(const v8bf*)(wbuf + (wc * 16 + kk) * 1024 + lane * 16);
                cacc = __builtin_amdgcn_mfma_f32_32x32x16_bf16(h[kk], b1, cacc, 0, 0, 0);
            }

            // ---- exp + row-sum accum + P write (bf16, frag-major, slot-XOR) ----
            #pragma unroll
            for (int r = 0; r < 16; ++r) {
                int tl = (r & 3) + 8 * (r >> 2) + 4 * hi;
                float e = __expf(cacc[r]);
                unsigned short ub = f2bf(e);
                ls[r] += __builtin_bit_cast(float, ((unsigned)ub) << 16);
                int slot = (tl + 32 * hb_w) ^ pw_sxor;
                *(unsigned short*)(lds + pw_base + slot * 16) = ub;
            }

            asm volatile("s_waitcnt lgkmcnt(0)" ::: "memory");  // P visible
            __builtin_amdgcn_sched_barrier(0);
            __builtin_amdgcn_s_barrier();

            // ---- GEMM2: O[32 t][128 d] += P @ W2  (A linear LDS, B from ring) ----
            #pragma unroll
            for (int kb = 0; kb < 4; ++kb) {
                int sl = lane ^ ((kb & 1) << 2) ^ (hi << 1);
                v8bf pa = *(const v8bf*)(lds + P_OFF + wr * 4096 + kb * 1024 + sl * 16);
                #pragma unroll
                for (int db = 0; db < 4; ++db)
                    o[db] = __builtin_amdgcn_mfma_f32_32x32x16_bf16(pa, ring[kb * 4 + db], o[db], 0, 0, 0);
            }

            // ---- ring refill for next iter (latency hides under next GEMM1) ----
            if (it + 1 < niter) {
                const char* src = w2g + (size_t)(it + 1) * 32768;
                #pragma unroll
                for (int kb = 0; kb < 4; ++kb)
                    #pragma unroll
                    for (int db = 0; db < 4; ++db)
                        ring[kb * 4 + db] =
                            *(const v8bf*)(src + (kb * 8 + wc * 4 + db) * 1024 + lane * 16);
            }

            asm volatile("s_waitcnt vmcnt(16)" ::: "memory");  // DMA done; ring flying
            __builtin_amdgcn_sched_barrier(0);
            __builtin_amdgcn_s_barrier();
        }

        // ---- epilogue: reduce row sums over 32 n-lanes, combine wc via LDS ----
        #pragma unroll
        for (int r = 0; r < 16; ++r) {
            float s = ls[r];
            s += __shfl_xor(s, 1);
            s += __shfl_xor(s, 2);
            s += __shfl_xor(s, 4);
            s += __shfl_xor(s, 8);
            s += __shfl_xor(s, 16);
            ls[r] = s;
        }
        if (l5 == 0) {
            #pragma unroll
            for (int r = 0; r < 16; ++r) {
                int tl = (r & 3) + 8 * (r >> 2) + 4 * hi;
                atomicAdd(&lsf[wr * 32 + tl], ls[r]);
            }
        }
        __syncthreads();

        #pragma unroll
        for (int r = 0; r < 16; ++r) {
            int tl = (r & 3) + 8 * (r >> 2) + 4 * hi;
            float inv = 1.0f / lsf[wr * 32 + tl];
            size_t row = (size_t)(t0 + wr * 32 + tl);
            #pragma unroll
            for (int db = 0; db < 4; ++db)
                outp[row * DD + wc * 128 + db * 32 + l5] = o[db][r] * inv;
        }
    }
}

extern "C" void kernel_launch(void* const* d_in, const int* in_sizes, int n_in,
                              void* d_out, int out_size, void* d_ws, size_t ws_size,
                              hipStream_t stream) {
    const float* in_intent = (const float*)d_in[0];
    const float* in_slot   = (const float*)d_in[1];
    // d_in[2] = mask (unused)
    const float* w_intent  = (const float*)d_in[3];
    const float* w_slot    = (const float*)d_in[4];
    float* out = (float*)d_out;
    char* wsb = (char*)d_ws;

    (void)hipFuncSetAttribute((const void*)label_attn_kernel,
                              hipFuncAttributeMaxDynamicSharedMemorySize, LDS_BYTES);

    // prep: 1536 frag-waves -> 384 blocks of 256
    prep_w_kernel<<<384, 256, 0, stream>>>(w_intent, w_slot, wsb);

    label_attn_kernel<<<dim3(TOK / TM, 1, 1), dim3(THREADS, 1, 1), LDS_BYTES, stream>>>(
        in_intent, in_slot, wsb, out);
}

// Round 6
// 179.321 us; speedup vs baseline: 1.2110x; 1.2110x over previous
//
#include <hip/hip_runtime.h>

// Label attention: out = softmax(H @ W^T) @ W, fused, bf16 MFMA, no-max softmax.
// R5: fix R3's register spills (VGPR capped at 128 by occupancy heuristic ->
// ~100 spilled regs -> scratch-bound, WRITE_SIZE 108MB vs 67MB output).
// Changes: amdgpu_waves_per_eu(2,2) pins 2 waves/EU (256 VGPR budget);
// W2 moved back to LDS via DMA from frag-major images (-64 VGPR, kills the
// 8x-redundant per-wave L2 streaming); dual GEMM1 accumulator for MFMA ILP.
// Per-wave counted vmcnt: 8 DMA loads/iter (4 Wt + 4 W2), mid vmcnt(8),
// post-GEMM2 vmcnt(4), 1-tile-deep prefetch across both barriers.

#define TM 128
#define DD 256
#define THREADS 512
#define TOK 32768

typedef __bf16 bf16t;
typedef bf16t v8bf __attribute__((ext_vector_type(8)));
typedef float v16f __attribute__((ext_vector_type(16)));

// LDS layout (byte offsets)
#define WT0   0        // Wt tile buf0: 32 frags * 1KB
#define WT1   32768    // Wt tile buf1
#define W20   65536    // W2 tile buf0: 32 frags * 1KB
#define W21   98304    // W2 tile buf1
#define P_OFF 131072   // P: 4 wr-groups * 4 kb-frags * 1KB
#define L_OFF 147456   // row sums: 128 * 4B
#define LDS_BYTES 147968

// ws layout: frag-major bf16 images (1KB per wave-frag = 64 lanes * 16B)
#define IWT 0          // intent Wt: 8 tiles * 32KB
#define SWT 262144     // slot  Wt: 16 tiles * 32KB
#define IW2 786432     // intent W2: 8 tiles * 32KB
#define SW2 1048576    // slot  W2: 16 tiles * 32KB

__device__ __forceinline__ unsigned short f2bf(float x) {
    unsigned u = __builtin_bit_cast(unsigned, x);
    unsigned r = u + 0x7fffu + ((u >> 16) & 1u);
    return (unsigned short)(r >> 16);
}

// ---- prep: build frag-major bf16 W images in ws (unchanged from R3) ----
// Wt frag (tile it, wc, kk): lane l holds W[it*64+wc*32+(l&31)][kk*16+(l>>5)*8+j]
// W2 frag (tile it, kb, db): lane l holds W[it*64+kb*16+(l>>5)*8+j][db*32+(l&31)]
__global__ __launch_bounds__(256) void prep_w_kernel(
    const float* __restrict__ w_int, const float* __restrict__ w_slot,
    char* __restrict__ wsb)
{
    int t = blockIdx.x * 256 + threadIdx.x;
    int w = t >> 6, lane = t & 63;
    int hi = lane >> 5, l5 = lane & 31;
    union { unsigned short u[8]; uint4 q; } pk;

    if (w < 768) {                       // Wt images (256 intent + 512 slot waves)
        int st   = (w >= 256);
        int widx = w - (st ? 256 : 0);
        int it = widx >> 5, fid = widx & 31;
        int wc = fid >> 4, kk = fid & 15;
        const float* W = st ? w_slot : w_int;
        int n  = it * 64 + wc * 32 + l5;
        int k0 = kk * 16 + hi * 8;
        #pragma unroll
        for (int j = 0; j < 8; ++j) pk.u[j] = f2bf(W[(size_t)n * DD + k0 + j]);
        char* dst = wsb + (st ? SWT : IWT) + (size_t)it * 32768 + fid * 1024 + lane * 16;
        *(uint4*)dst = pk.q;
    } else {                             // W2 images
        int w2 = w - 768;
        int st   = (w2 >= 256);
        int widx = w2 - (st ? 256 : 0);
        int it = widx >> 5, fid = widx & 31;
        int kb = fid >> 3, db = fid & 7;
        const float* W = st ? w_slot : w_int;
        int n0 = it * 64 + kb * 16 + hi * 8;
        int d  = db * 32 + l5;
        #pragma unroll
        for (int j = 0; j < 8; ++j) pk.u[j] = f2bf(W[(size_t)(n0 + j) * DD + d]);
        char* dst = wsb + (st ? SW2 : IW2) + (size_t)it * 32768 + fid * 1024 + lane * 16;
        *(uint4*)dst = pk.q;
    }
}

__global__ __launch_bounds__(THREADS)
__attribute__((amdgpu_waves_per_eu(2, 2)))
void label_attn_kernel(
    const float* __restrict__ in_intent,
    const float* __restrict__ in_slot,
    const char* __restrict__ wsb,
    float* __restrict__ out)
{
    extern __shared__ char lds[];

    const int tid  = threadIdx.x;
    const int lane = tid & 63;
    const int wid  = tid >> 6;
    const int wr   = wid >> 1;          // token group (32 rows each)
    const int wc   = wid & 1;           // n-half (GEMM1) / d-half (GEMM2)
    const int hi   = lane >> 5;
    const int l5   = lane & 31;
    const int t0   = blockIdx.x * TM;

    float* lsf = (float*)(lds + L_OFF);

    // P write-address invariants (frag-major with bijective slot XOR)
    const int kbl_w = (l5 >> 4) & 1;
    const int hb_w  = (l5 >> 3) & 1;
    const int pw_base = P_OFF + wr * 4096 + (wc * 2 + kbl_w) * 1024 + (l5 & 7) * 2;
    const int pw_sxor = (kbl_w << 2) ^ (hb_w << 1);

    for (int st = 0; st < 2; ++st) {
        __builtin_amdgcn_s_barrier();          // prev stream fully done
        if (tid < TM) lsf[tid] = 0.0f;

        const float* __restrict__ inp = st ? in_slot : in_intent;
        const char*  __restrict__ wtg = wsb + (st ? SWT : IWT);
        const char*  __restrict__ w2g = wsb + (st ? SW2 : IW2);
        const int niter = st ? 16 : 8;
        float* __restrict__ outp = out + (size_t)st * TOK * DD;

        // ---- H -> registers (16 A-frags: row = lane&31, k = hi*8 + kk*16) ----
        v8bf h[16];
        {
            const float* hp = inp + (size_t)(t0 + wr * 32 + l5) * DD + hi * 8;
            #pragma unroll
            for (int kk = 0; kk < 16; ++kk) {
                float4 a = *(const float4*)(hp + kk * 16);
                float4 b = *(const float4*)(hp + kk * 16 + 4);
                union { unsigned short u[8]; v8bf v; } pk;
                pk.u[0] = f2bf(a.x); pk.u[1] = f2bf(a.y);
                pk.u[2] = f2bf(a.z); pk.u[3] = f2bf(a.w);
                pk.u[4] = f2bf(b.x); pk.u[5] = f2bf(b.y);
                pk.u[6] = f2bf(b.z); pk.u[7] = f2bf(b.w);
                h[kk] = pk.v;
            }
        }

        // ---- prologue DMA: tile 0 (Wt -> WT0, W2 -> W20), full drain ----
        #pragma unroll
        for (int c = 0; c < 4; ++c) {
            int chunk = wid * 4 + c;
            __builtin_amdgcn_global_load_lds(
                (const __attribute__((address_space(1))) unsigned*)(wtg + chunk * 1024 + lane * 16),
                (__attribute__((address_space(3))) unsigned*)(lds + WT0 + chunk * 1024),
                16, 0, 0);
        }
        __builtin_amdgcn_sched_barrier(0);
        #pragma unroll
        for (int c = 0; c < 4; ++c) {
            int chunk = wid * 4 + c;
            __builtin_amdgcn_global_load_lds(
                (const __attribute__((address_space(1))) unsigned*)(w2g + chunk * 1024 + lane * 16),
                (__attribute__((address_space(3))) unsigned*)(lds + W20 + chunk * 1024),
                16, 0, 0);
        }
        __builtin_amdgcn_sched_barrier(0);
        asm volatile("s_waitcnt vmcnt(0)" ::: "memory");
        __builtin_amdgcn_sched_barrier(0);
        __builtin_amdgcn_s_barrier();

        v16f  o[4] = {};
        float ls[16] = {};

        for (int it = 0; it < niter; ++it) {
            const int cur = it & 1;
            char* wt_buf = lds + (cur ? WT1 : WT0);
            char* w2_buf = lds + (cur ? W21 : W20);

            // issue next-tile DMA into the alternate buffers (4 Wt, then 4 W2)
            if (it + 1 < niter) {
                const char* s1 = wtg + (size_t)(it + 1) * 32768;
                const char* s2 = w2g + (size_t)(it + 1) * 32768;
                char* d1 = lds + (cur ? WT0 : WT1);
                char* d2 = lds + (cur ? W20 : W21);
                #pragma unroll
                for (int c = 0; c < 4; ++c) {
                    int chunk = wid * 4 + c;
                    __builtin_amdgcn_global_load_lds(
                        (const __attribute__((address_space(1))) unsigned*)(s1 + chunk * 1024 + lane * 16),
                        (__attribute__((address_space(3))) unsigned*)(d1 + chunk * 1024),
                        16, 0, 0);
                }
                __builtin_amdgcn_sched_barrier(0);
                #pragma unroll
                for (int c = 0; c < 4; ++c) {
                    int chunk = wid * 4 + c;
                    __builtin_amdgcn_global_load_lds(
                        (const __attribute__((address_space(1))) unsigned*)(s2 + chunk * 1024 + lane * 16),
                        (__attribute__((address_space(3))) unsigned*)(d2 + chunk * 1024),
                        16, 0, 0);
                }
                __builtin_amdgcn_sched_barrier(0);
            }

            // ---- GEMM1: S[32 t][32 n] = H @ Wt^T, dual accumulator for ILP ----
            v16f c0 = {}, c1 = {};
            #pragma unroll
            for (int kk = 0; kk < 16; kk += 2) {
                v8bf b0 = *(const v8bf*)(wt_buf + (wc * 16 + kk) * 1024 + lane * 16);
                v8bf b1 = *(const v8bf*)(wt_buf + (wc * 16 + kk + 1) * 1024 + lane * 16);
                c0 = __builtin_amdgcn_mfma_f32_32x32x16_bf16(h[kk],     b0, c0, 0, 0, 0);
                c1 = __builtin_amdgcn_mfma_f32_32x32x16_bf16(h[kk + 1], b1, c1, 0, 0, 0);
            }
            v16f cacc = c0 + c1;

            // ---- exp + row-sum accum + P write (bf16, frag-major, slot-XOR) ----
            #pragma unroll
            for (int r = 0; r < 16; ++r) {
                int tl = (r & 3) + 8 * (r >> 2) + 4 * hi;
                float e = __expf(cacc[r]);
                unsigned short ub = f2bf(e);
                ls[r] += __builtin_bit_cast(float, ((unsigned)ub) << 16);
                int slot = (tl + 32 * hb_w) ^ pw_sxor;
                *(unsigned short*)(lds + pw_base + slot * 16) = ub;
            }

            // mid waits: W2(it) already resident; ensure own W2(it+1... ) ordering:
            // steady state: outstanding = W2(cur tile in final iter) or next-tile 8.
            if (it + 1 < niter) {
                asm volatile("s_waitcnt vmcnt(8)" ::: "memory");   // (no-op in steady state; bounds queue)
            } else {
                asm volatile("s_waitcnt vmcnt(0)" ::: "memory");   // final iter: drain W2(final)
            }
            asm volatile("s_waitcnt lgkmcnt(0)" ::: "memory");     // P visible
            __builtin_amdgcn_sched_barrier(0);
            __builtin_amdgcn_s_barrier();

            // ---- GEMM2: O[32 t][128 d] += P @ W2 (both linear LDS) ----
            #pragma unroll
            for (int kb = 0; kb < 4; ++kb) {
                int sl = lane ^ ((kb & 1) << 2) ^ (hi << 1);
                v8bf pa = *(const v8bf*)(lds + P_OFF + wr * 4096 + kb * 1024 + sl * 16);
                #pragma unroll
                for (int db = 0; db < 4; ++db) {
                    v8bf wb = *(const v8bf*)(w2_buf + (kb * 8 + wc * 4 + db) * 1024 + lane * 16);
                    o[db] = __builtin_amdgcn_mfma_f32_32x32x16_bf16(pa, wb, o[db], 0, 0, 0);
                }
            }

            // end: own Wt(it+1) must be done before any wave starts next GEMM1
            if (it + 1 < niter) {
                asm volatile("s_waitcnt vmcnt(4)" ::: "memory");
            }
            __builtin_amdgcn_sched_barrier(0);
            __builtin_amdgcn_s_barrier();
        }

        // ---- epilogue: reduce row sums over 32 n-lanes, combine wc via LDS ----
        #pragma unroll
        for (int r = 0; r < 16; ++r) {
            float s = ls[r];
            s += __shfl_xor(s, 1);
            s += __shfl_xor(s, 2);
            s += __shfl_xor(s, 4);
            s += __shfl_xor(s, 8);
            s += __shfl_xor(s, 16);
            ls[r] = s;
        }
        if (l5 == 0) {
            #pragma unroll
            for (int r = 0; r < 16; ++r) {
                int tl = (r & 3) + 8 * (r >> 2) + 4 * hi;
                atomicAdd(&lsf[wr * 32 + tl], ls[r]);
            }
        }
        __syncthreads();

        #pragma unroll
        for (int r = 0; r < 16; ++r) {
            int tl = (r & 3) + 8 * (r >> 2) + 4 * hi;
            float inv = 1.0f / lsf[wr * 32 + tl];
            size_t row = (size_t)(t0 + wr * 32 + tl);
            #pragma unroll
            for (int db = 0; db < 4; ++db)
                outp[row * DD + wc * 128 + db * 32 + l5] = o[db][r] * inv;
        }
    }
}

extern "C" void kernel_launch(void* const* d_in, const int* in_sizes, int n_in,
                              void* d_out, int out_size, void* d_ws, size_t ws_size,
                              hipStream_t stream) {
    const float* in_intent = (const float*)d_in[0];
    const float* in_slot   = (const float*)d_in[1];
    // d_in[2] = mask (unused)
    const float* w_intent  = (const float*)d_in[3];
    const float* w_slot    = (const float*)d_in[4];
    float* out = (float*)d_out;
    char* wsb = (char*)d_ws;

    (void)hipFuncSetAttribute((const void*)label_attn_kernel,
                              hipFuncAttributeMaxDynamicSharedMemorySize, LDS_BYTES);

    // prep: 1536 frag-waves -> 384 blocks of 256
    prep_w_kernel<<<384, 256, 0, stream>>>(w_intent, w_slot, wsb);

    label_attn_kernel<<<dim3(TOK / TM, 1, 1), dim3(THREADS, 1, 1), LDS_BYTES, stream>>>(
        in_intent, in_slot, wsb, out);
}